// Round 1
// baseline (6947.997 us; speedup 1.0000x reference)
//
#include <hip/hip_runtime.h>

#define TT 16384
#define BB 10
#define DD 3
#define HH 4
#define NITER 10
#define TBH (TT*BB*HH)   // 655360 per output tensor

// ---- DPP helpers (all lane movement stays in the VALU pipe) ----
template<int CTRL>
__device__ __forceinline__ float dpp_mov(float x) {
  return __int_as_float(__builtin_amdgcn_update_dpp(
      0, __float_as_int(x), CTRL, 0xF, 0xF, true));
}
template<int CTRL, int BM>
__device__ __forceinline__ float dpp_merge(float oldv, float x) {
  return __int_as_float(__builtin_amdgcn_update_dpp(
      __float_as_int(oldv), __float_as_int(x), CTRL, 0xF, BM, false));
}

__global__ void zero_out(float4* p, int n4) {
  int i = blockIdx.x * 256 + threadIdx.x;
  if (i < n4) p[i] = make_float4(0.f, 0.f, 0.f, 0.f);
}

// One chain (iter,b) = one 16-lane DPP row. Lane l in row: column k=l of the
// concatenated gate matrix [Wi|Wf|Wo|Wg] -> gg=l>>2 (0:i 1:f 2:o 3:g), unit j=l&3.
// Cell state c and h live on lanes 0-3 (unit j = lane).
__global__ __launch_bounds__(64) void mc_lstm(
    const float* __restrict__ x,  const float* __restrict__ zx, const float* __restrict__ zh,
    const float* __restrict__ Wi, const float* __restrict__ Ui,
    const float* __restrict__ Wf, const float* __restrict__ Uf,
    const float* __restrict__ Wo, const float* __restrict__ Uo,
    const float* __restrict__ Wg, const float* __restrict__ Ug,
    float* __restrict__ out)
{
  const int lane  = threadIdx.x & 63;
  const int chain = blockIdx.x * 4 + (lane >> 4);   // 25 blocks * 4 rows = 100 chains
  const int l  = lane & 15;
  const int j  = l & 3;
  const int gg = l >> 2;
  const int iter = chain / NITER;
  const int b    = chain - iter * NITER;

  const float L2E = 1.4426950408889634f;
  // Fold log2e AND the sigmoid's sign flip into the weights: for sigmoid lanes
  // G accumulates -x*log2e so sigma = rcp(1+exp2(G)); for the g (tanh) lane
  // G = 2*log2e*x so tanh = 1 - 2*rcp(1+exp2(G)).
  const float s = (gg == 3) ? 2.f * L2E : -L2E;

  const float* Wp = (gg == 0) ? Wi : (gg == 1) ? Wf : (gg == 2) ? Wo : Wg;
  const float* Up = (gg == 0) ? Ui : (gg == 1) ? Uf : (gg == 2) ? Uo : Ug;

  // Input-side weights with zx mask + scale folded in.
  const float Wz0 = Wp[0 * HH + j] * zx[iter * DD + 0] * s;
  const float Wz1 = Wp[1 * HH + j] * zx[iter * DD + 1] * s;
  const float Wz2 = Wp[2 * HH + j] * zx[iter * DD + 2] * s;

  // Recurrent weights with zh folded in, ordered by XOR offset so the
  // quad_perm-broadcast values line up without selects.
  const int m1 = j ^ 1, m2 = j ^ 2, m3 = j ^ 3;
  const float Ux0 = Up[j  * HH + j] * zh[iter * HH + j ] * s;
  const float Ux1 = Up[m1 * HH + j] * zh[iter * HH + m1] * s;
  const float Ux2 = Up[m2 * HH + j] * zh[iter * HH + m2] * s;
  const float Ux3 = Up[m3 * HH + j] * zh[iter * HH + m3] * s;

  // Per-lane output pointer: lanes 0-3 store o, 4-7 store h, 8-11 store c.
  float* sptr = out + ((gg == 0) ? 0 : (gg == 1) ? TBH : 2 * TBH) + b * HH + j;

  float h2 = 0.f, c = 0.f;
  const int bo = b * DD;
  float x0 = x[bo], x1 = x[bo + 1], x2 = x[bo + 2];
  int soff = 0;

  for (int t = 0; t < TT; ++t) {
    // Prefetch next timestep's input row (TT is pow2 -> cheap wrap, no OOB).
    const float* xrow = x + ((t + 1) & (TT - 1)) * (BB * DD);
    const float nx0 = xrow[bo], nx1 = xrow[bo + 1], nx2 = xrow[bo + 2];

    // Input projection (h-independent, schedules early).
    const float xp = fmaf(x2, Wz2, fmaf(x1, Wz1, x0 * Wz0));

    // Replicate h (valid on lanes 0-3) into all 4 banks of the row, then
    // all-to-all within each quad (XOR order).
    float hj = h2;
    hj = dpp_merge<0x114, 0x2>(hj, h2);   // row_shr:4  -> bank1
    hj = dpp_merge<0x118, 0x4>(hj, h2);   // row_shr:8  -> bank2
    hj = dpp_merge<0x11C, 0x8>(hj, h2);   // row_shr:12 -> bank3
    const float hx1 = dpp_mov<0xB1>(hj);  // quad_perm [1,0,3,2]
    const float hx2 = dpp_mov<0x4E>(hj);  // quad_perm [2,3,0,1]
    const float hx3 = dpp_mov<0x1B>(hj);  // quad_perm [3,2,1,0]

    // Gate pre-activation (scale/sign already folded into weights).
    const float G = fmaf(hj, Ux0, fmaf(hx1, Ux1, fmaf(hx2, Ux2, fmaf(hx3, Ux3, xp))));
    const float e = __builtin_amdgcn_exp2f(G);
    const float r = __builtin_amdgcn_rcpf(1.f + e);
    const float val = (gg == 3) ? fmaf(-2.f, r, 1.f) : r;  // sigmoid or tanh

    // Pull f, o, g down to lanes 0-3 (which hold i and the cell state).
    const float fv = dpp_mov<0x104>(val);  // row_shl:4
    const float ov = dpp_mov<0x108>(val);  // row_shl:8
    const float gv = dpp_mov<0x10C>(val);  // row_shl:12

    const float c2 = fmaf(fv, c, val * gv);
    const float e2 = __builtin_amdgcn_exp2f(c2 * (2.f * L2E));
    const float r2 = __builtin_amdgcn_rcpf(1.f + e2);
    const float th = fmaf(-2.f, r2, 1.f);          // tanh(c2)
    const float h2n = ov * th;

    // Distribute stores: lane j has o (ov), lane 4+j gets h, lane 8+j gets c.
    const float hs = dpp_mov<0x114>(h2n);  // row_shr:4
    const float cs = dpp_mov<0x118>(c2);   // row_shr:8
    const float vs = (gg == 0) ? ov : (gg == 1) ? hs : cs;
    if (l < 12) unsafeAtomicAdd(sptr + soff, vs * 0.1f);  // mean over NITER=10
    soff += BB * HH;

    h2 = h2n; c = c2;
    x0 = nx0; x1 = nx1; x2 = nx2;
  }
}

extern "C" void kernel_launch(void* const* d_in, const int* in_sizes, int n_in,
                              void* d_out, int out_size, void* d_ws, size_t ws_size,
                              hipStream_t stream) {
  const float* x  = (const float*)d_in[0];
  const float* zx = (const float*)d_in[1];
  const float* zh = (const float*)d_in[2];
  const float* Wi = (const float*)d_in[3];
  const float* Ui = (const float*)d_in[4];
  const float* Wf = (const float*)d_in[5];
  const float* Uf = (const float*)d_in[6];
  const float* Wo = (const float*)d_in[7];
  const float* Uo = (const float*)d_in[8];
  const float* Wg = (const float*)d_in[9];
  const float* Ug = (const float*)d_in[10];
  float* out = (float*)d_out;

  // d_out is poisoned before every call; atomic accumulation needs zeros.
  const int n4 = (3 * TBH) / 4;                 // 491520 float4s
  zero_out<<<n4 / 256, 256, 0, stream>>>((float4*)out, n4);

  mc_lstm<<<25, 64, 0, stream>>>(x, zx, zh, Wi, Ui, Wf, Uf, Wo, Uo, Wg, Ug, out);
}

// Round 2
// 2189.344 us; speedup vs baseline: 3.1736x; 3.1736x over previous
//
#include <hip/hip_runtime.h>

#define TT 16384
#define BB 10
#define DD 3
#define HH 4
#define NITER 10
#define TBH (TT*BB*HH)   // 655360 per output tensor
#define PF 16            // x-load pipeline depth (timesteps); TT % PF == 0

// ---- DPP helpers (all lane movement stays in the VALU pipe) ----
template<int CTRL>
__device__ __forceinline__ float dpp_mov(float x) {
  return __int_as_float(__builtin_amdgcn_update_dpp(
      0, __float_as_int(x), CTRL, 0xF, 0xF, true));
}
template<int CTRL, int BM>
__device__ __forceinline__ float dpp_merge(float oldv, float x) {
  return __int_as_float(__builtin_amdgcn_update_dpp(
      __float_as_int(oldv), __float_as_int(x), CTRL, 0xF, BM, false));
}

__global__ void zero_out(float4* p, int n4) {
  int i = blockIdx.x * 256 + threadIdx.x;
  if (i < n4) p[i] = make_float4(0.f, 0.f, 0.f, 0.f);
}

// One chain (iter,b) = one 16-lane DPP row. Lane l in row: column k=l of the
// concatenated gate matrix [Wi|Wf|Wo|Wg] -> gg=l>>2 (0:i 1:f 2:o 3:g), unit j=l&3.
// Cell state c and h live on lanes 0-3 (unit j = lane).
__global__ __launch_bounds__(64) void mc_lstm(
    const float* __restrict__ x,  const float* __restrict__ zx, const float* __restrict__ zh,
    const float* __restrict__ Wi, const float* __restrict__ Ui,
    const float* __restrict__ Wf, const float* __restrict__ Uf,
    const float* __restrict__ Wo, const float* __restrict__ Uo,
    const float* __restrict__ Wg, const float* __restrict__ Ug,
    float* __restrict__ out)
{
  const int lane  = threadIdx.x & 63;
  const int chain = blockIdx.x * 4 + (lane >> 4);   // 25 blocks * 4 rows = 100 chains
  const int l  = lane & 15;
  const int j  = l & 3;
  const int gg = l >> 2;
  const int iter = chain / NITER;
  const int b    = chain - iter * NITER;

  const float L2E = 1.4426950408889634f;
  // Fold log2e AND the sigmoid's sign flip into the weights: for sigmoid lanes
  // G accumulates -x*log2e so sigma = rcp(1+exp2(G)); for the g (tanh) lane
  // G = 2*log2e*x so tanh = 1 - 2*rcp(1+exp2(G)).
  const float s = (gg == 3) ? 2.f * L2E : -L2E;

  const float* Wp = (gg == 0) ? Wi : (gg == 1) ? Wf : (gg == 2) ? Wo : Wg;
  const float* Up = (gg == 0) ? Ui : (gg == 1) ? Uf : (gg == 2) ? Uo : Ug;

  // Input-side weights with zx mask + scale folded in.
  const float Wz0 = Wp[0 * HH + j] * zx[iter * DD + 0] * s;
  const float Wz1 = Wp[1 * HH + j] * zx[iter * DD + 1] * s;
  const float Wz2 = Wp[2 * HH + j] * zx[iter * DD + 2] * s;

  // Recurrent weights with zh folded in, ordered by XOR offset so the
  // quad_perm-broadcast values line up without selects.
  const int m1 = j ^ 1, m2 = j ^ 2, m3 = j ^ 3;
  const float Ux0 = Up[j  * HH + j] * zh[iter * HH + j ] * s;
  const float Ux1 = Up[m1 * HH + j] * zh[iter * HH + m1] * s;
  const float Ux2 = Up[m2 * HH + j] * zh[iter * HH + m2] * s;
  const float Ux3 = Up[m3 * HH + j] * zh[iter * HH + m3] * s;

  // Per-lane output pointer: lanes 0-3 store o, 4-7 store h, 8-11 store c.
  float* sptr = out + ((gg == 0) ? 0 : (gg == 1) ? TBH : 2 * TBH) + b * HH + j;

  float h2 = 0.f, c = 0.f;
  const int bo = b * DD;
  int soff = 0;

  // ---- register pipeline for x: group of PF timesteps in flight ----
  float fx0[PF], fx1[PF], fx2[PF];
#pragma unroll
  for (int u = 0; u < PF; ++u) {
    const float* xr = x + u * (BB * DD) + bo;
    fx0[u] = xr[0]; fx1[u] = xr[1]; fx2[u] = xr[2];
  }

  for (int g = 0; g < TT / PF; ++g) {
    // Issue next group's loads NOW; results are consumed only at the copy at
    // the end of this body, ~PF steps (~1.7k cycles) later -> latency hidden.
    float nx0[PF], nx1[PF], nx2[PF];
    const int nbase = ((g + 1) * PF) & (TT - 1);   // wraps on last group (valid addr)
#pragma unroll
    for (int u = 0; u < PF; ++u) {
      const float* xr = x + (nbase + u) * (BB * DD) + bo;
      nx0[u] = xr[0]; nx1[u] = xr[1]; nx2[u] = xr[2];
    }

#pragma unroll
    for (int u = 0; u < PF; ++u) {
      // Input projection (h-independent, schedules early).
      const float xp = fmaf(fx2[u], Wz2, fmaf(fx1[u], Wz1, fx0[u] * Wz0));

      // Replicate h (valid on lanes 0-3) into all 4 banks of the row, then
      // all-to-all within each quad (XOR order).
      float hj = h2;
      hj = dpp_merge<0x114, 0x2>(hj, h2);   // row_shr:4  -> bank1
      hj = dpp_merge<0x118, 0x4>(hj, h2);   // row_shr:8  -> bank2
      hj = dpp_merge<0x11C, 0x8>(hj, h2);   // row_shr:12 -> bank3
      const float hx1 = dpp_mov<0xB1>(hj);  // quad_perm [1,0,3,2]
      const float hx2 = dpp_mov<0x4E>(hj);  // quad_perm [2,3,0,1]
      const float hx3 = dpp_mov<0x1B>(hj);  // quad_perm [3,2,1,0]

      // Gate pre-activation (scale/sign already folded into weights).
      const float G = fmaf(hj, Ux0, fmaf(hx1, Ux1, fmaf(hx2, Ux2, fmaf(hx3, Ux3, xp))));
      const float e = __builtin_amdgcn_exp2f(G);
      const float r = __builtin_amdgcn_rcpf(1.f + e);
      const float val = (gg == 3) ? fmaf(-2.f, r, 1.f) : r;  // sigmoid or tanh

      // Pull f, o, g down to lanes 0-3 (which hold i and the cell state).
      const float fv = dpp_mov<0x104>(val);  // row_shl:4
      const float ov = dpp_mov<0x108>(val);  // row_shl:8
      const float gv = dpp_mov<0x10C>(val);  // row_shl:12

      const float c2 = fmaf(fv, c, val * gv);
      const float e2 = __builtin_amdgcn_exp2f(c2 * (2.f * L2E));
      const float r2 = __builtin_amdgcn_rcpf(1.f + e2);
      const float th = fmaf(-2.f, r2, 1.f);          // tanh(c2)
      const float h2n = ov * th;

      // Distribute stores: lane j has o (ov), lane 4+j gets h, lane 8+j gets c.
      const float hs = dpp_mov<0x114>(h2n);  // row_shr:4
      const float cs = dpp_mov<0x118>(c2);   // row_shr:8
      const float vs = (gg == 0) ? ov : (gg == 1) ? hs : cs;
      if (l < 12) unsafeAtomicAdd(sptr + soff, vs * 0.1f);  // mean over NITER=10
      soff += BB * HH;

      h2 = h2n; c = c2;
    }

    // Rotate pipeline (compiler renames; the vmcnt wait lands here, after the
    // PF-step compute, not inside it).
#pragma unroll
    for (int u = 0; u < PF; ++u) {
      fx0[u] = nx0[u]; fx1[u] = nx1[u]; fx2[u] = nx2[u];
    }
  }
}

extern "C" void kernel_launch(void* const* d_in, const int* in_sizes, int n_in,
                              void* d_out, int out_size, void* d_ws, size_t ws_size,
                              hipStream_t stream) {
  const float* x  = (const float*)d_in[0];
  const float* zx = (const float*)d_in[1];
  const float* zh = (const float*)d_in[2];
  const float* Wi = (const float*)d_in[3];
  const float* Ui = (const float*)d_in[4];
  const float* Wf = (const float*)d_in[5];
  const float* Uf = (const float*)d_in[6];
  const float* Wo = (const float*)d_in[7];
  const float* Uo = (const float*)d_in[8];
  const float* Wg = (const float*)d_in[9];
  const float* Ug = (const float*)d_in[10];
  float* out = (float*)d_out;

  // d_out is poisoned before every call; atomic accumulation needs zeros.
  const int n4 = (3 * TBH) / 4;                 // 491520 float4s
  zero_out<<<n4 / 256, 256, 0, stream>>>((float4*)out, n4);

  mc_lstm<<<25, 64, 0, stream>>>(x, zx, zh, Wi, Ui, Wf, Uf, Wo, Uo, Wg, Ug, out);
}